// Round 3
// baseline (201.037 us; speedup 1.0000x reference)
//
#include <hip/hip_runtime.h>

#define B_ 16
#define N_ 2048
#define M_ 2048
#define D_ 64
#define SCALE 0.125f

typedef short sv8 __attribute__((ext_vector_type(8)));
typedef short sv4 __attribute__((ext_vector_type(4)));
typedef float fv4 __attribute__((ext_vector_type(4)));

__device__ __forceinline__ short f2bf(float x) {
    union { float f; unsigned u; } a; a.f = x;
    unsigned r = a.u + 0x7FFFu + ((a.u >> 16) & 1u);
    return (short)(r >> 16);
}
__device__ __forceinline__ unsigned cvtpk(float lo, float hi) {
    unsigned r;
    asm("v_cvt_pk_bf16_f32 %0, %1, %2" : "=v"(r) : "v"(lo), "v"(hi));
    return r;
}
__device__ __forceinline__ float bflo(unsigned u) { return __uint_as_float(u << 16); }
__device__ __forceinline__ float bfhi(unsigned u) { return __uint_as_float(u & 0xffff0000u); }

// fp32 -> bf16 (RNE), 4 elems/thread
__global__ void conv_bf16(const float* __restrict__ in, short* __restrict__ outb) {
    int i = (blockIdx.x * 256 + threadIdx.x) * 4;
    float4 f = *(const float4*)(in + i);
    uint2 o; o.x = cvtpk(f.x, f.y); o.y = cvtpk(f.z, f.w);
    *(uint2*)(outb + i) = o;
}

// v[b][m][d] fp32 -> vt[b][d][m] bf16, 64x64 tiles through LDS
__global__ void conv_vt(const float* __restrict__ v, short* __restrict__ vt) {
    __shared__ short tile[64][65];
    int t = threadIdx.x;
    int b = blockIdx.x >> 5;
    int mt = (blockIdx.x & 31) << 6;
    for (int i = 0; i < 4; ++i) {
        int idx = i * 256 + t;
        int m = idx >> 4;
        int dq = (idx & 15) << 2;
        float4 f = *(const float4*)(v + ((size_t)(b * M_ + mt + m) * D_ + dq));
        tile[m][dq + 0] = f2bf(f.x); tile[m][dq + 1] = f2bf(f.y);
        tile[m][dq + 2] = f2bf(f.z); tile[m][dq + 3] = f2bf(f.w);
    }
    __syncthreads();
    for (int j = 0; j < 2; ++j) {
        int idx = j * 256 + t;
        int d = idx >> 3;
        int mq = (idx & 7) << 3;
        sv4 o0, o1;
        #pragma unroll
        for (int c = 0; c < 4; ++c) o0[c] = tile[mq + c][d];
        #pragma unroll
        for (int c = 0; c < 4; ++c) o1[c] = tile[mq + 4 + c][d];
        short* dst = vt + ((size_t)(b * D_ + d) * M_ + mt + mq);
        *(sv4*)(dst) = o0;
        *(sv4*)(dst + 4) = o1;
    }
}

// Pass 1: softmax denominators. Block = 64 rows (4 waves x 16), no LDS, no barriers.
__global__ __launch_bounds__(256) void attn_sums(
    const short* __restrict__ Qb, const short* __restrict__ Kb,
    float* __restrict__ rinv_g)
{
    const int tid = threadIdx.x;
    const int w = tid >> 6, lane = tid & 63;
    const int r = lane & 15, g = lane >> 4;
    const int b = blockIdx.x >> 5;
    const int n0 = ((blockIdx.x & 31) << 6) + (w << 4);

    const short* qbase = Qb + ((b * N_ + n0 + r) * D_ + g * 8);
    sv8 q0 = *(const sv8*)(qbase);
    sv8 q1 = *(const sv8*)(qbase + 32);
    const short* kbb = Kb + (size_t)b * M_ * D_;

    float lsum = 0.f;
    for (int m0 = 0; m0 < M_; m0 += 64) {
        #pragma unroll
        for (int s = 0; s < 4; ++s) {
            const short* ka = kbb + (m0 + s * 16 + r) * D_ + g * 8;
            sv8 k0 = *(const sv8*)ka;
            sv8 k1 = *(const sv8*)(ka + 32);
            fv4 acc = {0.f, 0.f, 0.f, 0.f};
            acc = __builtin_amdgcn_mfma_f32_16x16x32_bf16(k0, q0, acc, 0, 0, 0);
            acc = __builtin_amdgcn_mfma_f32_16x16x32_bf16(k1, q1, acc, 0, 0, 0);
            lsum += __expf(acc[0] * SCALE) + __expf(acc[1] * SCALE)
                  + __expf(acc[2] * SCALE) + __expf(acc[3] * SCALE);
        }
    }
    lsum += __shfl_xor(lsum, 16, 64);
    lsum += __shfl_xor(lsum, 32, 64);
    if (g == 0) rinv_g[b * N_ + n0 + r] = 1.f / lsum;
}

// Pass 2: streaming. Per wave: 16 rows, chunk of 64 m per iter:
//   S^T MFMA -> exp -> cvt_pk -> wave-private swizzled LDS tile (bf16 [16n][64m])
//   -> transposed float4 nontemporal attn stores + ds_read_b128 PV A-frags.
// No barriers anywhere.
__global__ __launch_bounds__(256) void attn_bulk(
    const short* __restrict__ Qb, const short* __restrict__ Kb,
    const short* __restrict__ Vt, const float* __restrict__ rinv_g,
    float* __restrict__ outp, float* __restrict__ attnp)
{
    __shared__ short Pt[4][2][1024];   // [wave][dbuf][16n*64m], swizzled

    const int tid = threadIdx.x;
    const int w = tid >> 6, lane = tid & 63;
    const int r = lane & 15, g = lane >> 4;
    const int b = blockIdx.x >> 5;
    const int n0 = ((blockIdx.x & 31) << 6) + (w << 4);

    const short* qbase = Qb + ((b * N_ + n0 + r) * D_ + g * 8);
    sv8 q0 = *(const sv8*)(qbase);
    sv8 q1 = *(const sv8*)(qbase + 32);

    float rinv = rinv_g[b * N_ + n0 + r];
    const int n_st = lane >> 2, mq = lane & 3;
    float rinv_st = __shfl(rinv, n_st, 64);

    char* lds = (char*)&Pt[w][0][0];

    // byte = n*128 + ((m>>3 ^ (n&7))<<4) + (m&7)*2
    int wb[4], ra[2], ab[4];
    #pragma unroll
    for (int s = 0; s < 4; ++s)
        wb[s] = r * 128 + (((s * 2 + (g >> 1)) ^ (r & 7)) << 4) + ((g & 1) * 8);
    #pragma unroll
    for (int c = 0; c < 2; ++c)
        ra[c] = r * 128 + (((c * 4 + g) ^ (r & 7)) << 4);
    #pragma unroll
    for (int c2 = 0; c2 < 4; ++c2)
        ab[c2] = n_st * 128 + (((c2 * 2 + (mq >> 1)) ^ (n_st & 7)) << 4) + ((mq & 1) * 8);

    fv4 ac0 = {0.f,0.f,0.f,0.f}, ac1 = {0.f,0.f,0.f,0.f};
    fv4 ac2 = {0.f,0.f,0.f,0.f}, ac3 = {0.f,0.f,0.f,0.f};

    const short* kbb = Kb + (size_t)b * M_ * D_;
    const short* vbb = Vt + (size_t)b * D_ * M_;
    float* arow = attnp + (size_t)(b * N_ + n0 + n_st) * M_ + mq * 4;

    int buf = 0;
    for (int m0 = 0; m0 < M_; m0 += 64, buf ^= 1) {
        char* ldsb = lds + (buf << 11);

        #pragma unroll
        for (int s = 0; s < 4; ++s) {
            const short* ka = kbb + (m0 + s * 16 + r) * D_ + g * 8;
            sv8 k0 = *(const sv8*)ka;
            sv8 k1 = *(const sv8*)(ka + 32);
            fv4 acc = {0.f, 0.f, 0.f, 0.f};
            acc = __builtin_amdgcn_mfma_f32_16x16x32_bf16(k0, q0, acc, 0, 0, 0);
            acc = __builtin_amdgcn_mfma_f32_16x16x32_bf16(k1, q1, acc, 0, 0, 0);
            float p0 = __expf(acc[0] * SCALE), p1 = __expf(acc[1] * SCALE);
            float p2 = __expf(acc[2] * SCALE), p3 = __expf(acc[3] * SCALE);
            uint2 pk; pk.x = cvtpk(p0, p1); pk.y = cvtpk(p2, p3);
            *(uint2*)(ldsb + wb[s]) = pk;
        }

        // transposed, normalized attn stores: lane covers row n_st, m = mq*4 + c2*16
        #pragma unroll
        for (int c2 = 0; c2 < 4; ++c2) {
            uint2 pv = *(const uint2*)(ldsb + ab[c2]);
            fv4 o;
            o[0] = bflo(pv.x) * rinv_st; o[1] = bfhi(pv.x) * rinv_st;
            o[2] = bflo(pv.y) * rinv_st; o[3] = bfhi(pv.y) * rinv_st;
            __builtin_nontemporal_store(o, (fv4*)(arow + m0 + c2 * 16));
        }

        // PV accumulate: A-frag = 8 consecutive m of row r
        #pragma unroll
        for (int c = 0; c < 2; ++c) {
            sv8 pa = *(const sv8*)(ldsb + ra[c]);
            const short* vb0 = vbb + r * M_ + m0 + c * 32 + g * 8;
            ac0 = __builtin_amdgcn_mfma_f32_16x16x32_bf16(pa, *(const sv8*)(vb0),            ac0, 0, 0, 0);
            ac1 = __builtin_amdgcn_mfma_f32_16x16x32_bf16(pa, *(const sv8*)(vb0 + 16 * M_), ac1, 0, 0, 0);
            ac2 = __builtin_amdgcn_mfma_f32_16x16x32_bf16(pa, *(const sv8*)(vb0 + 32 * M_), ac2, 0, 0, 0);
            ac3 = __builtin_amdgcn_mfma_f32_16x16x32_bf16(pa, *(const sv8*)(vb0 + 48 * M_), ac3, 0, 0, 0);
        }
    }

    // epilogue: out[n][d] = acc * rinv[n];  n = g*4+reg, d = dsub*16 + r
    float* obase = outp + (size_t)(b * N_ + n0 + g * 4) * D_ + r;
    #pragma unroll
    for (int reg = 0; reg < 4; ++reg) {
        float ri = __shfl(rinv, g * 4 + reg, 64);
        __builtin_nontemporal_store(ac0[reg] * ri, obase + reg * D_);
        __builtin_nontemporal_store(ac1[reg] * ri, obase + reg * D_ + 16);
        __builtin_nontemporal_store(ac2[reg] * ri, obase + reg * D_ + 32);
        __builtin_nontemporal_store(ac3[reg] * ri, obase + reg * D_ + 48);
    }
}

extern "C" void kernel_launch(void* const* d_in, const int* in_sizes, int n_in,
                              void* d_out, int out_size, void* d_ws, size_t ws_size,
                              hipStream_t stream) {
    const float* q = (const float*)d_in[0];
    const float* k = (const float*)d_in[1];
    const float* v = (const float*)d_in[2];
    float* outp = (float*)d_out;
    float* attnp = outp + (size_t)B_ * N_ * D_;

    short* Qb = (short*)d_ws;                       // 4 MiB
    short* Kb = Qb + (size_t)B_ * N_ * D_;          // 4 MiB
    short* Vt = Kb + (size_t)B_ * M_ * D_;          // 4 MiB (transposed [b][d][m])
    float* rinv_g = (float*)(Vt + (size_t)B_ * M_ * D_);  // 512 KiB

    conv_bf16<<<2048, 256, 0, stream>>>(q, Qb);
    conv_bf16<<<2048, 256, 0, stream>>>(k, Kb);
    conv_vt<<<512, 256, 0, stream>>>(v, Vt);
    attn_sums<<<512, 256, 0, stream>>>(Qb, Kb, rinv_g);
    attn_bulk<<<512, 256, 0, stream>>>(Qb, Kb, Vt, rinv_g, outp, attnp);
}